// Round 2
// baseline (534.230 us; speedup 1.0000x reference)
//
#include <hip/hip_runtime.h>
#include <stdint.h>

// Fused shifted-window attention, one workgroup (4 waves) per 7x7 window.
// B=32, H=W=112, C=128, heads=4, d=32, N=49 (padded to 64 rows for MFMA).
// FP32 global I/O; bf16 MFMA compute, fp32 accumulation.
//
// v2 (transpose-free): GEMM1 computes q^T,k^T swapped (W·X^T) and v normal
// (X·Wv^T) so the C-layout fragments feed mfma_16x16x16 directly:
//   S^T = K·Q^T   (A = k^T C-frags, B = q^T C-frags)    -- no LDS round trip
//   O^T = V^T·P^T (A = v C-frags,   B = exp(S^T) regs)  -- no LDS round trip
// Softmax per token = in-lane 16-sum + 2 shfl_xor. O^T C-frags pack 4
// consecutive features -> 8B LDS writes into O[token][128]; proj is swapped
// (Wp·O^T) so staging writes are also 8B packs. 3 barriers total.
// exp -> exp2 with log2(e) folded into q-scale and the bias table.
//
// v3: v2 spilled to scratch (VGPR capped at 64 = 8 waves/SIMD target; WRITE_SIZE
// showed ~190 MB of non-output HBM writes). LDS (34816 B) caps us at 4 blocks/CU
// anyway, so pin codegen with amdgpu_waves_per_eu(4,4) -> 128-VGPR budget, and
// drop the e[4] fp32 array in phase 2 (pack P to bf16 per-mt immediately).

typedef __attribute__((ext_vector_type(8))) short short8;          // 8 bf16 (K=32 A/B frag)
typedef __attribute__((ext_vector_type(8))) unsigned short ushort8;
typedef __attribute__((ext_vector_type(4))) short short4v;         // 4 bf16 (K=16 A/B frag)
typedef __attribute__((ext_vector_type(4))) float f32x4;
typedef __attribute__((ext_vector_type(2))) float float2v;
typedef __attribute__((ext_vector_type(2))) unsigned uint2v;
typedef __attribute__((ext_vector_type(2))) __bf16 bf16x2;

#define MFMA32(a, b, c) __builtin_amdgcn_mfma_f32_16x16x32_bf16((a), (b), (c), 0, 0, 0)

#if __has_builtin(__builtin_amdgcn_mfma_f32_16x16x16bf16_1k)
#define MFMA16(a, b, c) __builtin_amdgcn_mfma_f32_16x16x16bf16_1k((a), (b), (c), 0, 0, 0)
#else
__device__ __forceinline__ f32x4 mfma16_fb(short4v a, short4v b, f32x4 c) {
  f32x4 d;
  asm volatile("v_mfma_f32_16x16x16_bf16 %0, %1, %2, %3" : "=v"(d) : "v"(a), "v"(b), "v"(c));
  return d;
}
#define MFMA16(a, b, c) mfma16_fb((a), (b), (c))
#endif

#if __has_builtin(__builtin_amdgcn_exp2f)
#define EXP2F(x) __builtin_amdgcn_exp2f(x)
#else
#define EXP2F(x) __expf(0.6931471805599453f * (x))
#endif

#define LOG2E 1.4426950408889634f
#define SCQ   0.25503486f          // d^-0.5 * log2(e)
#define MASKV 144.26950408889634f  // 100 * log2(e)

// pair fp32 -> packed bf16x2 (RNE); written as vector fptrunc so the
// compiler emits v_cvt_pk_bf16_f32 (guide m240: casts, not inline asm)
__device__ __forceinline__ unsigned pk2bf(float a, float b) {
  float2v t; t.x = a; t.y = b;
  return __builtin_bit_cast(unsigned, __builtin_convertvector(t, bf16x2));
}
__device__ __forceinline__ float bf2f(unsigned short h) {
  union { unsigned u; float f; } v; v.u = ((unsigned)h) << 16;
  return v.f;
}
__device__ __forceinline__ short8 ld8(const unsigned short* p) {
  return __builtin_bit_cast(short8, *(const ushort8*)p);
}
__device__ __forceinline__ short4v mk4(unsigned lo, unsigned hi) {
  uint2v u; u.x = lo; u.y = hi;
  return __builtin_bit_cast(short4v, u);
}

// ---- workspace layout (bytes) ----
// bias4 fp32 [4 cls][4 h][16 mt*nt][64 lane] x f32x4 : @0, 262144 B  (S^T orient)
// qkvw bf16 [384][128]  : @262144, 98304 B
// projw bf16 [128][128] : @360448, 32768 B   (total 393216 B)
#define WS_W_OFF 262144

// ================= prologue: weight convert + bias/mask precompute ==========
// bias4 holds log2e*(rel_bias + shift_mask) in the C-layout of S^T:
//   tile (mt = key tile, nt = token tile); lane: col = token nt*16+l16 (clamped
//   to 48), rows = key mt*16+quad*4+r; key > 48 -> -1e30 (exp2 -> 0).
__global__ __launch_bounds__(256, 1)
void prep_kernel(const float* __restrict__ qkvw, const float* __restrict__ projw,
                 const float* __restrict__ tbl,
                 float* __restrict__ bias4, unsigned short* __restrict__ wbf) {
  const int tid = blockIdx.x * 256 + threadIdx.x;
  if (tid < 16384) {
    const int lane = tid & 63;
    const int mtnt = (tid >> 6) & 15;
    const int h    = (tid >> 10) & 3;
    const int cls  = (tid >> 12) & 3;          // (wy==15)*2 + (wx==15)
    const int mt = mtnt >> 2, nt = mtnt & 3;   // mt: key tile, nt: token tile
    const int m0 = mt * 16 + (lane >> 4) * 4;  // key row base
    int n = nt * 16 + (lane & 15);             // token col
    if (n > 48) n = 48;                        // clamp matches clamped B-cols
    const int cy = cls >> 1, cx = cls & 1;
    const int it = n / 7, jt = n - (n / 7) * 7;
    const int rt = (cy ? (it < 4 ? 1 : 2) : 0) * 3 + (cx ? (jt < 4 ? 1 : 2) : 0);
    f32x4 v;
#pragma unroll
    for (int r = 0; r < 4; ++r) {
      const int m = m0 + r;
      if (m > 48) { v[r] = -1.0e30f; continue; }   // pad keys -> exp2 = 0
      const int im = m / 7, jm = m - (m / 7) * 7;
      const int rm = (cy ? (im < 4 ? 1 : 2) : 0) * 3 + (cx ? (jm < 4 ? 1 : 2) : 0);
      const int idx = (it - im + 6) * 13 + (jt - jm + 6);  // bias[query=n][key=m]
      float bv = tbl[idx * 4 + h] * LOG2E;
      if (rm != rt) bv -= MASKV;                 // shift mask (symmetric)
      v[r] = bv;
    }
    *(f32x4*)(bias4 + tid * 4) = v;
  } else {
    const int e = tid - 16384;                   // weight f32x4 chunks
    const float* src; int dst;
    if (e < 12288) { src = qkvw + e * 4;             dst = e * 4; }
    else           { src = projw + (e - 12288) * 4;  dst = 49152 + (e - 12288) * 4; }
    f32x4 a = *(const f32x4*)src;
    uint2v s; s.x = pk2bf(a[0], a[1]); s.y = pk2bf(a[2], a[3]);
    *(uint2v*)(wbf + dst) = s;
  }
}

// ---- LDS (ushort units): region1 xw/stag [64][136] @0, region2 O [64][136]
// @8704; total 17408 us = 34816 B -> 4 blocks/CU (the LDS-dictated limit; pin
// codegen to it so the allocator gets the full 128-VGPR budget, no spill) ----
__global__ __launch_bounds__(256)
__attribute__((amdgpu_waves_per_eu(4, 4)))
void swin_attn_kernel(const float* __restrict__ x,
                      const float* __restrict__ qkvb,
                      const float* __restrict__ projb,
                      const float* __restrict__ bias4,
                      const unsigned short* __restrict__ wbf,
                      float* __restrict__ out) {
  __shared__ unsigned short sm[17408];
  unsigned short* __restrict__ xw = sm;          // X window, later proj staging
  unsigned short* __restrict__ ob = sm + 8704;   // O [token][128] (+8 pad)

  const int t    = threadIdx.x;
  const int lane = t & 63;
  const int wv   = t >> 6;      // wave id 0..3 == head
  const int quad = lane >> 4;
  const int l16  = lane & 15;

  const int wid = blockIdx.x;
  const int b   = wid >> 8;     // batch
  const int w   = wid & 255;
  const int wy  = w >> 4;
  const int wx  = w & 15;

  // ---- phase 0: shifted window load (roll folded into index), fp32 -> bf16 ----
  {
    const int c4 = t & 31, pr = t >> 5;
#pragma unroll
    for (int p = 0; p < 7; ++p) {
      const int n = p * 8 + pr;
      if (n < 49) {
        const int i = n / 7, j = n - (n / 7) * 7;
        const int gi = (wy * 7 + i + 3) % 112;
        const int gj = (wx * 7 + j + 3) % 112;
        f32x4 v = *(const f32x4*)(x + ((((long)b * 112 + gi) * 112 + gj) << 7) + c4 * 4);
        uint2v s; s.x = pk2bf(v[0], v[1]); s.y = pk2bf(v[2], v[3]);
        *(uint2v*)&xw[n * 136 + c4 * 4] = s;
      }
    }
  }
  __syncthreads();   // A: xw ready

  // bf16 C-fragments kept in registers across the attention phase:
  //   qbf/kbf[ft][nt]: q^T/k^T tile (feature tile ft, token tile nt), 2 u32
  //   vbf[kt][dt]:     v    tile (key tile kt, feature tile dt),      2 u32
  unsigned qbf[2][4][2], kbf[2][4][2], vbf[4][2][2];

  // ---- phase 1a: q^T, k^T = W · X^T (swapped; xw A-frags serve as B-frags) ----
#pragma unroll
  for (int qk = 0; qk < 2; ++qk) {
    const int wrow0 = qk * 128 + wv * 32;
#pragma unroll
    for (int ft = 0; ft < 2; ++ft) {
      const unsigned short* wp = wbf + ((wrow0 + ft * 16 + l16) << 7) + quad * 8;
      const short8 wf0 = ld8(wp), wf1 = ld8(wp + 32), wf2 = ld8(wp + 64), wf3 = ld8(wp + 96);
      const f32x4 bias = *(const f32x4*)(qkvb + wrow0 + ft * 16 + quad * 4);
#pragma unroll
      for (int nt = 0; nt < 4; ++nt) {
        int ar = nt * 16 + l16; if (ar > 48) ar = 48;       // pad tokens -> row 48
        const unsigned short* ap = &xw[ar * 136 + quad * 8];
        f32x4 acc = {0.f, 0.f, 0.f, 0.f};
        acc = MFMA32(wf0, ld8(ap), acc);
        acc = MFMA32(wf1, ld8(ap + 32), acc);
        acc = MFMA32(wf2, ld8(ap + 64), acc);
        acc = MFMA32(wf3, ld8(ap + 96), acc);
        if (qk == 0) {   // q: fold d^-0.5 * log2e
          qbf[ft][nt][0] = pk2bf((acc[0] + bias[0]) * SCQ, (acc[1] + bias[1]) * SCQ);
          qbf[ft][nt][1] = pk2bf((acc[2] + bias[2]) * SCQ, (acc[3] + bias[3]) * SCQ);
        } else {
          kbf[ft][nt][0] = pk2bf(acc[0] + bias[0], acc[1] + bias[1]);
          kbf[ft][nt][1] = pk2bf(acc[2] + bias[2], acc[3] + bias[3]);
        }
      }
    }
  }
  // ---- phase 1b: v = X · Wv^T (normal; C-frags are A-frags of V^T) ----
#pragma unroll
  for (int dt = 0; dt < 2; ++dt) {
    const int fcol = 256 + wv * 32 + dt * 16 + l16;
    const unsigned short* wp = wbf + (fcol << 7) + quad * 8;
    const short8 wf0 = ld8(wp), wf1 = ld8(wp + 32), wf2 = ld8(wp + 64), wf3 = ld8(wp + 96);
    const float bias = qkvb[fcol];
#pragma unroll
    for (int kt = 0; kt < 4; ++kt) {
      int ar = kt * 16 + l16; if (ar > 48) ar = 48;
      const unsigned short* ap = &xw[ar * 136 + quad * 8];
      f32x4 acc = {0.f, 0.f, 0.f, 0.f};
      acc = MFMA32(ld8(ap), wf0, acc);
      acc = MFMA32(ld8(ap + 32), wf1, acc);
      acc = MFMA32(ld8(ap + 64), wf2, acc);
      acc = MFMA32(ld8(ap + 96), wf3, acc);
      vbf[kt][dt][0] = pk2bf(acc[0] + bias, acc[1] + bias);
      vbf[kt][dt][1] = pk2bf(acc[2] + bias, acc[3] + bias);
    }
  }

  // ---- phase 2: attention, fully in registers, per token-tile ----
  // S^T = K·Q^T via mfma16x16x16; C init = precomputed bias (S^T orientation).
  // Softmax: no max-pass (|scores| small, exact invariance), unnormalized P
  // packed to bf16 immediately (per-mt, no fp32 e[] array -> lower pressure),
  // 1/sum applied at O^T epilogue (lane owns one token col).
  const float* bb = bias4 + ((((wy == 15) * 2 + (wx == 15)) * 4 + wv) << 12);
#pragma unroll
  for (int nt = 0; nt < 4; ++nt) {
    unsigned pf[4][2];
    float psum = 0.f;
#pragma unroll
    for (int mt = 0; mt < 4; ++mt) {
      f32x4 s = *(const f32x4*)(bb + ((((mt << 2) | nt) << 6) + lane) * 4);
      s = MFMA16(mk4(kbf[0][mt][0], kbf[0][mt][1]), mk4(qbf[0][nt][0], qbf[0][nt][1]), s);
      s = MFMA16(mk4(kbf[1][mt][0], kbf[1][mt][1]), mk4(qbf[1][nt][0], qbf[1][nt][1]), s);
      const float e0 = EXP2F(s[0]);
      const float e1 = EXP2F(s[1]);
      const float e2 = EXP2F(s[2]);
      const float e3 = EXP2F(s[3]);
      psum += (e0 + e1) + (e2 + e3);
      pf[mt][0] = pk2bf(e0, e1);
      pf[mt][1] = pk2bf(e2, e3);
    }
    psum += __shfl_xor(psum, 16);     // token's 64 keys live in 4 lanes
    psum += __shfl_xor(psum, 32);
    const float inv = 1.0f / psum;
    // O^T = V^T · P^T; C-frag rows = 4 consecutive features -> 8B packed write
#pragma unroll
    for (int dt = 0; dt < 2; ++dt) {
      f32x4 o = {0.f, 0.f, 0.f, 0.f};
#pragma unroll
      for (int mt = 0; mt < 4; ++mt)
        o = MFMA16(mk4(vbf[mt][dt][0], vbf[mt][dt][1]), mk4(pf[mt][0], pf[mt][1]), o);
      uint2v pkd;
      pkd.x = pk2bf(o[0] * inv, o[1] * inv);
      pkd.y = pk2bf(o[2] * inv, o[3] * inv);
      *(uint2v*)&ob[(nt * 16 + l16) * 136 + wv * 32 + dt * 16 + quad * 4] = pkd;
    }
  }
  __syncthreads();   // C: all heads' O ready (and all xw reads done)

  // ---- phase 3: proj swapped (out^T = Wp · O^T); stage into xw region ----
#pragma unroll
  for (int sub = 0; sub < 2; ++sub) {
    const int mtile = wv * 2 + sub;   // out-feature tile
    const unsigned short* wp = wbf + 49152 + ((mtile * 16 + l16) << 7) + quad * 8;
    const short8 wf0 = ld8(wp), wf1 = ld8(wp + 32), wf2 = ld8(wp + 64), wf3 = ld8(wp + 96);
    const f32x4 bias = *(const f32x4*)(projb + mtile * 16 + quad * 4);
#pragma unroll
    for (int nt = 0; nt < 4; ++nt) {
      const unsigned short* op = &ob[(nt * 16 + l16) * 136 + quad * 8];
      f32x4 acc = {0.f, 0.f, 0.f, 0.f};
      acc = MFMA32(wf0, ld8(op), acc);
      acc = MFMA32(wf1, ld8(op + 32), acc);
      acc = MFMA32(wf2, ld8(op + 64), acc);
      acc = MFMA32(wf3, ld8(op + 96), acc);
      uint2v pkd;
      pkd.x = pk2bf(acc[0] + bias[0], acc[1] + bias[1]);
      pkd.y = pk2bf(acc[2] + bias[2], acc[3] + bias[3]);
      *(uint2v*)&xw[(nt * 16 + l16) * 136 + mtile * 16 + quad * 4] = pkd;
    }
  }
  __syncthreads();   // E: staging ready

  // ---- phase 4: coalesced fp32 store (inverse roll == same index mapping) ----
  {
    const int c4 = t & 31, pr = t >> 5;
#pragma unroll
    for (int p = 0; p < 7; ++p) {
      const int n = p * 8 + pr;
      if (n < 49) {
        const int i = n / 7, j = n - (n / 7) * 7;
        const int gi = (wy * 7 + i + 3) % 112;
        const int gj = (wx * 7 + j + 3) % 112;
        uint2v s = *(const uint2v*)&xw[n * 136 + c4 * 4];
        f32x4 v;
        v[0] = bf2f((unsigned short)(s.x & 0xFFFFu));
        v[1] = bf2f((unsigned short)(s.x >> 16));
        v[2] = bf2f((unsigned short)(s.y & 0xFFFFu));
        v[3] = bf2f((unsigned short)(s.y >> 16));
        *(f32x4*)(out + ((((long)b * 112 + gi) * 112 + gj) << 7) + c4 * 4) = v;
      }
    }
  }
}

extern "C" void kernel_launch(void* const* d_in, const int* in_sizes, int n_in,
                              void* d_out, int out_size, void* d_ws, size_t ws_size,
                              hipStream_t stream) {
  (void)in_sizes; (void)n_in; (void)out_size; (void)ws_size;
  const float* x     = (const float*)d_in[0];
  const float* qkvw  = (const float*)d_in[1];
  const float* qkvb  = (const float*)d_in[2];
  const float* projw = (const float*)d_in[3];
  const float* projb = (const float*)d_in[4];
  const float* tbl   = (const float*)d_in[5];
  float* outp = (float*)d_out;

  float*          ws_bias = (float*)d_ws;
  unsigned short* ws_w    = (unsigned short*)((char*)d_ws + WS_W_OFF);

  prep_kernel<<<128, 256, 0, stream>>>(qkvw, projw, tbl, ws_bias, ws_w);
  swin_attn_kernel<<<8192, 256, 0, stream>>>(x, qkvb, projb, ws_bias, ws_w, outp);
}

// Round 3
// 481.726 us; speedup vs baseline: 1.1090x; 1.1090x over previous
//
#include <hip/hip_runtime.h>
#include <stdint.h>

// Fused shifted-window attention, one workgroup (4 waves) per 7x7 window.
// B=32, H=W=112, C=128, heads=4, d=32, N=49 (padded to 64 rows for MFMA).
// FP32 global I/O; bf16 MFMA compute, fp32 accumulation.
//
// v2 (transpose-free): GEMM1 computes q^T,k^T swapped (W·X^T) and v normal
// (X·Wv^T) so the C-layout fragments feed mfma_16x16x16 directly:
//   S^T = K·Q^T   (A = k^T C-frags, B = q^T C-frags)    -- no LDS round trip
//   O^T = V^T·P^T (A = v C-frags,   B = exp(S^T) regs)  -- no LDS round trip
// v3: tried amdgpu_waves_per_eu(4,4) -> no effect (VGPR stuck at 64, ~100 B/thr
// scratch traffic: WRITE_SIZE 405 MB vs 200 MB output).
// v4: cut peak register demand instead of fighting the allocator:
//   order = qk GEMM -> ALL S+softmax (q/k die, packed P kept: 32 regs)
//         -> v GEMM (xw still valid, not overwritten until phase 3)
//         -> PV -> proj. Max two fragment sets live at once (~75 regs peak).
//   Plus __launch_bounds__(256, 2): min 2 waves/EU -> 256-VGPR budget (128
//   arch even under a 50/50 unified-file AGPR split). LDS still caps real
//   occupancy at 4 blocks/CU, unaffected by VGPR counts <= 128.

typedef __attribute__((ext_vector_type(8))) short short8;          // 8 bf16 (K=32 A/B frag)
typedef __attribute__((ext_vector_type(8))) unsigned short ushort8;
typedef __attribute__((ext_vector_type(4))) short short4v;         // 4 bf16 (K=16 A/B frag)
typedef __attribute__((ext_vector_type(4))) float f32x4;
typedef __attribute__((ext_vector_type(2))) float float2v;
typedef __attribute__((ext_vector_type(2))) unsigned uint2v;
typedef __attribute__((ext_vector_type(2))) __bf16 bf16x2;

#define MFMA32(a, b, c) __builtin_amdgcn_mfma_f32_16x16x32_bf16((a), (b), (c), 0, 0, 0)

#if __has_builtin(__builtin_amdgcn_mfma_f32_16x16x16bf16_1k)
#define MFMA16(a, b, c) __builtin_amdgcn_mfma_f32_16x16x16bf16_1k((a), (b), (c), 0, 0, 0)
#else
__device__ __forceinline__ f32x4 mfma16_fb(short4v a, short4v b, f32x4 c) {
  f32x4 d;
  asm volatile("v_mfma_f32_16x16x16_bf16 %0, %1, %2, %3" : "=v"(d) : "v"(a), "v"(b), "v"(c));
  return d;
}
#define MFMA16(a, b, c) mfma16_fb((a), (b), (c))
#endif

#if __has_builtin(__builtin_amdgcn_exp2f)
#define EXP2F(x) __builtin_amdgcn_exp2f(x)
#else
#define EXP2F(x) __expf(0.6931471805599453f * (x))
#endif

#define LOG2E 1.4426950408889634f
#define SCQ   0.25503486f          // d^-0.5 * log2(e)
#define MASKV 144.26950408889634f  // 100 * log2(e)

// pair fp32 -> packed bf16x2 (RNE); vector fptrunc -> v_cvt_pk_bf16_f32
__device__ __forceinline__ unsigned pk2bf(float a, float b) {
  float2v t; t.x = a; t.y = b;
  return __builtin_bit_cast(unsigned, __builtin_convertvector(t, bf16x2));
}
__device__ __forceinline__ float bf2f(unsigned short h) {
  union { unsigned u; float f; } v; v.u = ((unsigned)h) << 16;
  return v.f;
}
__device__ __forceinline__ short8 ld8(const unsigned short* p) {
  return __builtin_bit_cast(short8, *(const ushort8*)p);
}
__device__ __forceinline__ short4v mk4(unsigned lo, unsigned hi) {
  uint2v u; u.x = lo; u.y = hi;
  return __builtin_bit_cast(short4v, u);
}

// ---- workspace layout (bytes) ----
// bias4 fp32 [4 cls][4 h][16 mt*nt][64 lane] x f32x4 : @0, 262144 B  (S^T orient)
// qkvw bf16 [384][128]  : @262144, 98304 B
// projw bf16 [128][128] : @360448, 32768 B   (total 393216 B)
#define WS_W_OFF 262144

// ================= prologue: weight convert + bias/mask precompute ==========
// bias4 holds log2e*(rel_bias + shift_mask) in the C-layout of S^T:
//   tile (mt = key tile, nt = token tile); lane: col = token nt*16+l16 (clamped
//   to 48), rows = key mt*16+quad*4+r; key > 48 -> -1e30 (exp2 -> 0).
__global__ __launch_bounds__(256, 1)
void prep_kernel(const float* __restrict__ qkvw, const float* __restrict__ projw,
                 const float* __restrict__ tbl,
                 float* __restrict__ bias4, unsigned short* __restrict__ wbf) {
  const int tid = blockIdx.x * 256 + threadIdx.x;
  if (tid < 16384) {
    const int lane = tid & 63;
    const int mtnt = (tid >> 6) & 15;
    const int h    = (tid >> 10) & 3;
    const int cls  = (tid >> 12) & 3;          // (wy==15)*2 + (wx==15)
    const int mt = mtnt >> 2, nt = mtnt & 3;   // mt: key tile, nt: token tile
    const int m0 = mt * 16 + (lane >> 4) * 4;  // key row base
    int n = nt * 16 + (lane & 15);             // token col
    if (n > 48) n = 48;                        // clamp matches clamped B-cols
    const int cy = cls >> 1, cx = cls & 1;
    const int it = n / 7, jt = n - (n / 7) * 7;
    const int rt = (cy ? (it < 4 ? 1 : 2) : 0) * 3 + (cx ? (jt < 4 ? 1 : 2) : 0);
    f32x4 v;
#pragma unroll
    for (int r = 0; r < 4; ++r) {
      const int m = m0 + r;
      if (m > 48) { v[r] = -1.0e30f; continue; }   // pad keys -> exp2 = 0
      const int im = m / 7, jm = m - (m / 7) * 7;
      const int rm = (cy ? (im < 4 ? 1 : 2) : 0) * 3 + (cx ? (jm < 4 ? 1 : 2) : 0);
      const int idx = (it - im + 6) * 13 + (jt - jm + 6);  // bias[query=n][key=m]
      float bv = tbl[idx * 4 + h] * LOG2E;
      if (rm != rt) bv -= MASKV;                 // shift mask (symmetric)
      v[r] = bv;
    }
    *(f32x4*)(bias4 + tid * 4) = v;
  } else {
    const int e = tid - 16384;                   // weight f32x4 chunks
    const float* src; int dst;
    if (e < 12288) { src = qkvw + e * 4;             dst = e * 4; }
    else           { src = projw + (e - 12288) * 4;  dst = 49152 + (e - 12288) * 4; }
    f32x4 a = *(const f32x4*)src;
    uint2v s; s.x = pk2bf(a[0], a[1]); s.y = pk2bf(a[2], a[3]);
    *(uint2v*)(wbf + dst) = s;
  }
}

// ---- LDS (ushort units): region1 xw/stag [64][136] @0, region2 O [64][136]
// @8704; total 17408 us = 34816 B -> 4 blocks/CU (the real occupancy cap) ----
__global__ __launch_bounds__(256, 2)
void swin_attn_kernel(const float* __restrict__ x,
                      const float* __restrict__ qkvb,
                      const float* __restrict__ projb,
                      const float* __restrict__ bias4,
                      const unsigned short* __restrict__ wbf,
                      float* __restrict__ out) {
  __shared__ unsigned short sm[17408];
  unsigned short* __restrict__ xw = sm;          // X window, later proj staging
  unsigned short* __restrict__ ob = sm + 8704;   // O [token][128] (+8 pad)

  const int t    = threadIdx.x;
  const int lane = t & 63;
  const int wv   = t >> 6;      // wave id 0..3 == head
  const int quad = lane >> 4;
  const int l16  = lane & 15;

  const int wid = blockIdx.x;
  const int b   = wid >> 8;     // batch
  const int w   = wid & 255;
  const int wy  = w >> 4;
  const int wx  = w & 15;

  // ---- phase 0: shifted window load (roll folded into index), fp32 -> bf16 ----
  {
    const int c4 = t & 31, pr = t >> 5;
#pragma unroll
    for (int p = 0; p < 7; ++p) {
      const int n = p * 8 + pr;
      if (n < 49) {
        const int i = n / 7, j = n - (n / 7) * 7;
        const int gi = (wy * 7 + i + 3) % 112;
        const int gj = (wx * 7 + j + 3) % 112;
        f32x4 v = *(const f32x4*)(x + ((((long)b * 112 + gi) * 112 + gj) << 7) + c4 * 4);
        uint2v s; s.x = pk2bf(v[0], v[1]); s.y = pk2bf(v[2], v[3]);
        *(uint2v*)&xw[n * 136 + c4 * 4] = s;
      }
    }
  }
  __syncthreads();   // A: xw ready

  // ---- phase 1a: q^T, k^T = W · X^T (swapped; xw A-frags serve as B-frags) ----
  // qbf/kbf[ft][nt]: q^T/k^T tile (feature tile ft, token tile nt), 2 u32 each.
  unsigned qbf[2][4][2], kbf[2][4][2];
#pragma unroll
  for (int qk = 0; qk < 2; ++qk) {
    const int wrow0 = qk * 128 + wv * 32;
#pragma unroll
    for (int ft = 0; ft < 2; ++ft) {
      const unsigned short* wp = wbf + ((wrow0 + ft * 16 + l16) << 7) + quad * 8;
      const short8 wf0 = ld8(wp), wf1 = ld8(wp + 32), wf2 = ld8(wp + 64), wf3 = ld8(wp + 96);
      const f32x4 bias = *(const f32x4*)(qkvb + wrow0 + ft * 16 + quad * 4);
#pragma unroll
      for (int nt = 0; nt < 4; ++nt) {
        int ar = nt * 16 + l16; if (ar > 48) ar = 48;       // pad tokens -> row 48
        const unsigned short* ap = &xw[ar * 136 + quad * 8];
        f32x4 acc = {0.f, 0.f, 0.f, 0.f};
        acc = MFMA32(wf0, ld8(ap), acc);
        acc = MFMA32(wf1, ld8(ap + 32), acc);
        acc = MFMA32(wf2, ld8(ap + 64), acc);
        acc = MFMA32(wf3, ld8(ap + 96), acc);
        if (qk == 0) {   // q: fold d^-0.5 * log2e
          qbf[ft][nt][0] = pk2bf((acc[0] + bias[0]) * SCQ, (acc[1] + bias[1]) * SCQ);
          qbf[ft][nt][1] = pk2bf((acc[2] + bias[2]) * SCQ, (acc[3] + bias[3]) * SCQ);
        } else {
          kbf[ft][nt][0] = pk2bf(acc[0] + bias[0], acc[1] + bias[1]);
          kbf[ft][nt][1] = pk2bf(acc[2] + bias[2], acc[3] + bias[3]);
        }
      }
    }
  }

  // ---- phase 2a: S^T = K·Q^T + bias (mfma16), softmax -> packed P ----
  // q/k die here; only pf (32 u32) + inv (4 f32) survive. No max-pass
  // (|scores| small, exact invariance), unnormalized P, 1/sum deferred.
  unsigned pf[4][4][2];
  float inv[4];
  {
    const float* bb = bias4 + ((((wy == 15) * 2 + (wx == 15)) * 4 + wv) << 12);
#pragma unroll
    for (int nt = 0; nt < 4; ++nt) {
      float psum = 0.f;
#pragma unroll
      for (int mt = 0; mt < 4; ++mt) {
        f32x4 s = *(const f32x4*)(bb + ((((mt << 2) | nt) << 6) + lane) * 4);
        s = MFMA16(mk4(kbf[0][mt][0], kbf[0][mt][1]), mk4(qbf[0][nt][0], qbf[0][nt][1]), s);
        s = MFMA16(mk4(kbf[1][mt][0], kbf[1][mt][1]), mk4(qbf[1][nt][0], qbf[1][nt][1]), s);
        const float e0 = EXP2F(s[0]);
        const float e1 = EXP2F(s[1]);
        const float e2 = EXP2F(s[2]);
        const float e3 = EXP2F(s[3]);
        psum += (e0 + e1) + (e2 + e3);
        pf[nt][mt][0] = pk2bf(e0, e1);
        pf[nt][mt][1] = pk2bf(e2, e3);
      }
      psum += __shfl_xor(psum, 16);     // token's 64 keys live in 4 lanes
      psum += __shfl_xor(psum, 32);
      inv[nt] = 1.0f / psum;
    }
  }

  // ---- phase 1b (deferred): v = X · Wv^T; xw is still intact here ----
  // C-frags of v are the A-frags of V^T. Only pf+vbf live now.
  unsigned vbf[4][2][2];
#pragma unroll
  for (int dt = 0; dt < 2; ++dt) {
    const int fcol = 256 + wv * 32 + dt * 16 + l16;
    const unsigned short* wp = wbf + (fcol << 7) + quad * 8;
    const short8 wf0 = ld8(wp), wf1 = ld8(wp + 32), wf2 = ld8(wp + 64), wf3 = ld8(wp + 96);
    const float bias = qkvb[fcol];
#pragma unroll
    for (int kt = 0; kt < 4; ++kt) {
      int ar = kt * 16 + l16; if (ar > 48) ar = 48;
      const unsigned short* ap = &xw[ar * 136 + quad * 8];
      f32x4 acc = {0.f, 0.f, 0.f, 0.f};
      acc = MFMA32(ld8(ap), wf0, acc);
      acc = MFMA32(ld8(ap + 32), wf1, acc);
      acc = MFMA32(ld8(ap + 64), wf2, acc);
      acc = MFMA32(ld8(ap + 96), wf3, acc);
      vbf[kt][dt][0] = pk2bf(acc[0] + bias, acc[1] + bias);
      vbf[kt][dt][1] = pk2bf(acc[2] + bias, acc[3] + bias);
    }
  }

  // ---- phase 2b: O^T = V^T · P^T; 4 consecutive features -> 8B packed write ----
#pragma unroll
  for (int nt = 0; nt < 4; ++nt) {
#pragma unroll
    for (int dt = 0; dt < 2; ++dt) {
      f32x4 o = {0.f, 0.f, 0.f, 0.f};
#pragma unroll
      for (int mt = 0; mt < 4; ++mt)
        o = MFMA16(mk4(vbf[mt][dt][0], vbf[mt][dt][1]), mk4(pf[nt][mt][0], pf[nt][mt][1]), o);
      uint2v pkd;
      pkd.x = pk2bf(o[0] * inv[nt], o[1] * inv[nt]);
      pkd.y = pk2bf(o[2] * inv[nt], o[3] * inv[nt]);
      *(uint2v*)&ob[(nt * 16 + l16) * 136 + wv * 32 + dt * 16 + quad * 4] = pkd;
    }
  }
  __syncthreads();   // C: all heads' O ready (and all xw reads done)

  // ---- phase 3: proj swapped (out^T = Wp · O^T); stage into xw region ----
#pragma unroll
  for (int sub = 0; sub < 2; ++sub) {
    const int mtile = wv * 2 + sub;   // out-feature tile
    const unsigned short* wp = wbf + 49152 + ((mtile * 16 + l16) << 7) + quad * 8;
    const short8 wf0 = ld8(wp), wf1 = ld8(wp + 32), wf2 = ld8(wp + 64), wf3 = ld8(wp + 96);
    const f32x4 bias = *(const f32x4*)(projb + mtile * 16 + quad * 4);
#pragma unroll
    for (int nt = 0; nt < 4; ++nt) {
      const unsigned short* op = &ob[(nt * 16 + l16) * 136 + quad * 8];
      f32x4 acc = {0.f, 0.f, 0.f, 0.f};
      acc = MFMA32(wf0, ld8(op), acc);
      acc = MFMA32(wf1, ld8(op + 32), acc);
      acc = MFMA32(wf2, ld8(op + 64), acc);
      acc = MFMA32(wf3, ld8(op + 96), acc);
      uint2v pkd;
      pkd.x = pk2bf(acc[0] + bias[0], acc[1] + bias[1]);
      pkd.y = pk2bf(acc[2] + bias[2], acc[3] + bias[3]);
      *(uint2v*)&xw[(nt * 16 + l16) * 136 + mtile * 16 + quad * 4] = pkd;
    }
  }
  __syncthreads();   // E: staging ready

  // ---- phase 4: coalesced fp32 store (inverse roll == same index mapping) ----
  {
    const int c4 = t & 31, pr = t >> 5;
#pragma unroll
    for (int p = 0; p < 7; ++p) {
      const int n = p * 8 + pr;
      if (n < 49) {
        const int i = n / 7, j = n - (n / 7) * 7;
        const int gi = (wy * 7 + i + 3) % 112;
        const int gj = (wx * 7 + j + 3) % 112;
        uint2v s = *(const uint2v*)&xw[n * 136 + c4 * 4];
        f32x4 v;
        v[0] = bf2f((unsigned short)(s.x & 0xFFFFu));
        v[1] = bf2f((unsigned short)(s.x >> 16));
        v[2] = bf2f((unsigned short)(s.y & 0xFFFFu));
        v[3] = bf2f((unsigned short)(s.y >> 16));
        *(f32x4*)(out + ((((long)b * 112 + gi) * 112 + gj) << 7) + c4 * 4) = v;
      }
    }
  }
}

extern "C" void kernel_launch(void* const* d_in, const int* in_sizes, int n_in,
                              void* d_out, int out_size, void* d_ws, size_t ws_size,
                              hipStream_t stream) {
  (void)in_sizes; (void)n_in; (void)out_size; (void)ws_size;
  const float* x     = (const float*)d_in[0];
  const float* qkvw  = (const float*)d_in[1];
  const float* qkvb  = (const float*)d_in[2];
  const float* projw = (const float*)d_in[3];
  const float* projb = (const float*)d_in[4];
  const float* tbl   = (const float*)d_in[5];
  float* outp = (float*)d_out;

  float*          ws_bias = (float*)d_ws;
  unsigned short* ws_w    = (unsigned short*)((char*)d_ws + WS_W_OFF);

  prep_kernel<<<128, 256, 0, stream>>>(qkvw, projw, tbl, ws_bias, ws_w);
  swin_attn_kernel<<<8192, 256, 0, stream>>>(x, qkvb, projb, ws_bias, ws_w, outp);
}